// Round 5
// baseline (605.539 us; speedup 1.0000x reference)
//
#include <hip/hip_runtime.h>

#define NN 50000
#define IN_DIM 128
#define HID 64
#define NLAYERS 3
#define NB 1563  // ceil(NN/32) bins for CSR build

typedef __attribute__((ext_vector_type(8))) short bf16x8;
typedef __attribute__((ext_vector_type(4))) float f32x4;

__device__ __forceinline__ unsigned f2bf(float f) {
    unsigned u = __float_as_uint(f);
    return (u + 0x7fffu + ((u >> 16) & 1u)) >> 16;  // round-to-nearest-even
}

// Pack two fp32 -> packed bf16 pair (a -> lo, b -> hi), round-half-up.
__device__ __forceinline__ unsigned pk2bf(float a, float b) {
    return __builtin_amdgcn_perm(__float_as_uint(b) + 0x8000u,
                                 __float_as_uint(a) + 0x8000u, 0x07060302u);
}

// q = packed bf16 pair. Returns packed bf16 pair of relu(q + p).
__device__ __forceinline__ unsigned pack_r(unsigned q, float pA, float pB) {
    float lo = fmaxf(__uint_as_float(q << 16) + pA, 0.f);
    float hi = fmaxf(__uint_as_float(q & 0xffff0000u) + pB, 0.f);
    return pk2bf(lo, hi);
}

__global__ void k_zero(int* __restrict__ p, int n) {
    int i = blockIdx.x * blockDim.x + threadIdx.x;
    if (i < n) p[i] = 0;
}

// Per-bin histogram (bin = dst >> 5), LDS-aggregated.
__global__ void k_binhist(const int* __restrict__ dst, int* __restrict__ bincnt, int E) {
    __shared__ int lh[NB];
    for (int i = threadIdx.x; i < NB; i += 256) lh[i] = 0;
    __syncthreads();
    for (int e = blockIdx.x * 256 + threadIdx.x; e < E; e += gridDim.x * 256)
        atomicAdd(&lh[dst[e] >> 5], 1);
    __syncthreads();
    for (int i = threadIdx.x; i < NB; i += 256)
        if (lh[i]) atomicAdd(&bincnt[i], lh[i]);
}

// Exclusive scan of bincnt[NB] -> binoff, single block.
__global__ void k_binscan(const int* __restrict__ bincnt, int* __restrict__ binoff) {
    __shared__ int s[256];
    int t = threadIdx.x;
    int carry = 0;
    for (int c0 = 0; c0 < NB; c0 += 256) {
        int v = (c0 + t < NB) ? bincnt[c0 + t] : 0;
        s[t] = v;
        __syncthreads();
        for (int d = 1; d < 256; d <<= 1) {
            int a = (t >= d) ? s[t - d] : 0;
            __syncthreads();
            s[t] += a;
            __syncthreads();
        }
        if (c0 + t < NB) binoff[c0 + t] = carry + s[t] - v;
        carry += s[255];
        __syncthreads();
    }
}

// Append (dstlow5 << 16 | src) to bin streams. ~1563 active streams -> lines
// fill before eviction (vs 50000-stream scatter's 17x write amplification).
__global__ void k_binscatter(const int* __restrict__ src, const int* __restrict__ dst,
                             const int* __restrict__ binoff, int* __restrict__ bincur,
                             unsigned* __restrict__ bscratch, int E) {
    int e = blockIdx.x * 256 + threadIdx.x;
    if (e < E) {
        int d = dst[e];
        int bin = d >> 5;
        int pos = atomicAdd(&bincur[bin], 1);
        bscratch[binoff[bin] + pos] = ((unsigned)(d & 31) << 16) | (unsigned)src[e];
    }
}

// One block per bin: LDS counting-sort by dst-low-5; emit ushort csr + deg/off.
__global__ void __launch_bounds__(256) k_binsort(
    const unsigned* __restrict__ bscratch, const int* __restrict__ bincnt,
    const int* __restrict__ binoff, unsigned short* __restrict__ csr,
    int* __restrict__ deg, int* __restrict__ off) {
    __shared__ unsigned entries[1024];
    __shared__ unsigned short sorted[1024];
    __shared__ int cnt[32];
    int bin = blockIdx.x, t = threadIdx.x;
    int n = bincnt[bin], boff = binoff[bin];
    for (int i = t; i < n; i += 256) entries[i] = bscratch[boff + i];
    if (t < 32) cnt[t] = 0;
    __syncthreads();
    for (int i = t; i < n; i += 256) atomicAdd(&cnt[entries[i] >> 16], 1);
    __syncthreads();
    if (t < 32) {
        int c = cnt[t];
        int s = c;
#pragma unroll
        for (int d = 1; d < 32; d <<= 1) {
            int o = __shfl_up(s, d, 64);
            if (t >= d) s += o;
        }
        int node = bin * 32 + t;
        if (node < NN) {
            deg[node] = c;
            off[node] = boff + s - c;
        }
        cnt[t] = s - c;  // reuse as cursor
    }
    __syncthreads();
    for (int i = t; i < n; i += 256) {
        unsigned e = entries[i];
        int p = atomicAdd(&cnt[e >> 16], 1);
        sorted[p] = (unsigned short)(e & 0xffffu);
    }
    __syncthreads();
    for (int i = t; i < n; i += 256) csr[boff + i] = sorted[i];
}

// h = x @ Wp + bp. Wave handles 4 nodes; weight loads amortized 4x.
__global__ void k_proj4(const float* __restrict__ x, const float* __restrict__ Wp,
                        const float* __restrict__ bp, float* __restrict__ h) {
    __shared__ float xs[4][4][IN_DIM];
    int lane = threadIdx.x & 63, wave = threadIdx.x >> 6;
    int node0 = blockIdx.x * 16 + wave * 4;
#pragma unroll
    for (int n = 0; n < 4; n++) {
        xs[wave][n][lane]      = x[(size_t)(node0 + n) * IN_DIM + lane];
        xs[wave][n][64 + lane] = x[(size_t)(node0 + n) * IN_DIM + 64 + lane];
    }
    __syncthreads();
    float bv = bp[lane];
    float acc[4] = {bv, bv, bv, bv};
#pragma unroll
    for (int k = 0; k < IN_DIM; k += 4) {
        float w0 = Wp[(k + 0) * HID + lane];
        float w1 = Wp[(k + 1) * HID + lane];
        float w2 = Wp[(k + 2) * HID + lane];
        float w3 = Wp[(k + 3) * HID + lane];
#pragma unroll
        for (int n = 0; n < 4; n++) {
            float4 xv = *(const float4*)&xs[wave][n][k];
            acc[n] = fmaf(xv.x, w0, acc[n]);
            acc[n] = fmaf(xv.y, w1, acc[n]);
            acc[n] = fmaf(xv.z, w2, acc[n]);
            acc[n] = fmaf(xv.w, w3, acc[n]);
        }
    }
#pragma unroll
    for (int n = 0; n < 4; n++) h[(size_t)(node0 + n) * HID + lane] = acc[n];
}

// [P|Q] = h @ [W1top-W1bot | W1bot] + [b1|0] via MFMA. One wave per 16 nodes.
__global__ void __launch_bounds__(256) k_pq_mfma(
    const float* __restrict__ h, const float* __restrict__ W1,
    const float* __restrict__ b1, float* __restrict__ P,
    unsigned short* __restrict__ Qb, int layer) {
    int lane = threadIdx.x & 63, wave = threadIdx.x >> 6;
    int col = lane & 15, quad = lane >> 4;
    int node0 = (blockIdx.x * 4 + wave) * 16;
    if (node0 >= NN) return;
    const float* W1l = W1 + layer * 2 * HID * HID;

    bf16x8 bfr[8][2];
#pragma unroll
    for (int t = 0; t < 8; t++)
#pragma unroll
        for (int hf = 0; hf < 2; hf++) {
            uint4 u;
#pragma unroll
            for (int jp = 0; jp < 4; jp++) {
                int k0 = hf * 32 + quad * 8 + jp * 2;
                float w0, w1v;
                if (t < 4) {
                    int n = t * 16 + col;
                    w0  = W1l[k0 * HID + n] - W1l[(HID + k0) * HID + n];
                    w1v = W1l[(k0 + 1) * HID + n] - W1l[(HID + k0 + 1) * HID + n];
                } else {
                    int n = (t - 4) * 16 + col;
                    w0  = W1l[(HID + k0) * HID + n];
                    w1v = W1l[(HID + k0 + 1) * HID + n];
                }
                ((unsigned*)&u)[jp] = pk2bf(w0, w1v);
            }
            bfr[t][hf] = __builtin_bit_cast(bf16x8, u);
        }

    const float* hrow = h + (size_t)(node0 + col) * HID;
    float4 ha0 = *(const float4*)(hrow + quad * 8);
    float4 ha1 = *(const float4*)(hrow + quad * 8 + 4);
    float4 hb0 = *(const float4*)(hrow + 32 + quad * 8);
    float4 hb1 = *(const float4*)(hrow + 32 + quad * 8 + 4);
    uint4 au, bu;
    au.x = pk2bf(ha0.x, ha0.y); au.y = pk2bf(ha0.z, ha0.w);
    au.z = pk2bf(ha1.x, ha1.y); au.w = pk2bf(ha1.z, ha1.w);
    bu.x = pk2bf(hb0.x, hb0.y); bu.y = pk2bf(hb0.z, hb0.w);
    bu.z = pk2bf(hb1.x, hb1.y); bu.w = pk2bf(hb1.z, hb1.w);
    bf16x8 a0 = __builtin_bit_cast(bf16x8, au);
    bf16x8 a1 = __builtin_bit_cast(bf16x8, bu);

#pragma unroll
    for (int t = 0; t < 8; t++) {
        f32x4 c = __builtin_amdgcn_mfma_f32_16x16x32_bf16(a0, bfr[t][0], (f32x4)(0.f), 0, 0, 0);
        c = __builtin_amdgcn_mfma_f32_16x16x32_bf16(a1, bfr[t][1], c, 0, 0, 0);
        if (t < 4) {
            float bv = b1[layer * HID + t * 16 + col];
#pragma unroll
            for (int r = 0; r < 4; r++)
                P[(size_t)(node0 + quad * 4 + r) * HID + t * 16 + col] = c[r] + bv;
        } else {
#pragma unroll
            for (int r = 0; r < 4; r++)
                Qb[(size_t)(node0 + quad * 4 + r) * HID + (t - 4) * 16 + col] =
                    (unsigned short)f2bf(c[r]);
        }
    }
}

// One wave per dst node. 16 edges/batch via mfma_f32_16x16x32_bf16.
// Pad lanes replicate edge b0 (valid). When fin!=0, also emit out = h@Wo+bo.
__global__ void __launch_bounds__(256) k_edge(
    const float* __restrict__ P, const unsigned short* __restrict__ Qb,
    const float* __restrict__ W2, const float* __restrict__ b2,
    const int* __restrict__ off, const int* __restrict__ deg,
    const unsigned short* __restrict__ csr, float* __restrict__ h, int layer, int nw,
    int fin, const float* __restrict__ Wo, const float* __restrict__ bo,
    float* __restrict__ outp) {
    int lane = threadIdx.x & 63;
    int col = lane & 15, quad = lane >> 4;
    int wid = (blockIdx.x * blockDim.x + threadIdx.x) >> 6;

    const float* W2l = W2 + layer * HID * HID;
    bf16x8 bfr[4][2];
#pragma unroll
    for (int t = 0; t < 4; t++)
#pragma unroll
        for (int hf = 0; hf < 2; hf++) {
            uint4 u;
#pragma unroll
            for (int jp = 0; jp < 4; jp++) {
                int k0 = hf * 32 + quad * 8 + jp * 2;
                ((unsigned*)&u)[jp] = pk2bf(W2l[k0 * HID + t * 16 + col],
                                            W2l[(k0 + 1) * HID + t * 16 + col]);
            }
            bfr[t][hf] = __builtin_bit_cast(bf16x8, u);
        }
    float b2v = b2[layer * HID + lane];
    float wov = fin ? Wo[lane] : 0.f;

    for (int node = wid; node < NN; node += nw) {
        int start = __builtin_amdgcn_readfirstlane(off[node]);
        int cnt   = __builtin_amdgcn_readfirstlane(deg[node]);
        float res = h[(size_t)node * HID + lane];
        float outv = 0.f;
        if (cnt > 0) {
            const float4* prow = (const float4*)(P + (size_t)node * HID);
            float4 pA = prow[quad * 2], pB = prow[quad * 2 + 1];
            float4 pC = prow[8 + quad * 2], pD = prow[8 + quad * 2 + 1];
            f32x4 mx[4];
#pragma unroll
            for (int t = 0; t < 4; t++) mx[t] = (f32x4)(-3.4e38f);
            for (int b0 = 0; b0 < cnt; b0 += 16) {
                int idx = b0 + col;
                int s = csr[start + (idx < cnt ? idx : b0)];
                const uint4* qrow = (const uint4*)(Qb + (size_t)s * HID);
                uint4 q0 = qrow[quad];
                uint4 q1 = qrow[4 + quad];
                uint4 a0u, a1u;
                a0u.x = pack_r(q0.x, pA.x, pA.y);
                a0u.y = pack_r(q0.y, pA.z, pA.w);
                a0u.z = pack_r(q0.z, pB.x, pB.y);
                a0u.w = pack_r(q0.w, pB.z, pB.w);
                a1u.x = pack_r(q1.x, pC.x, pC.y);
                a1u.y = pack_r(q1.y, pC.z, pC.w);
                a1u.z = pack_r(q1.z, pD.x, pD.y);
                a1u.w = pack_r(q1.w, pD.z, pD.w);
                bf16x8 a0 = __builtin_bit_cast(bf16x8, a0u);
                bf16x8 a1 = __builtin_bit_cast(bf16x8, a1u);
#pragma unroll
                for (int t = 0; t < 4; t++) {
                    f32x4 c = __builtin_amdgcn_mfma_f32_16x16x32_bf16(
                        a0, bfr[t][0], (f32x4)(0.f), 0, 0, 0);
                    c = __builtin_amdgcn_mfma_f32_16x16x32_bf16(
                        a1, bfr[t][1], c, 0, 0, 0);
#pragma unroll
                    for (int r = 0; r < 4; r++)
                        mx[t][r] = fmaxf(mx[t][r], c[r]);
                }
            }
            float v[4];
#pragma unroll
            for (int t = 0; t < 4; t++) {
                v[t] = fmaxf(fmaxf(mx[t][0], mx[t][1]), fmaxf(mx[t][2], mx[t][3]));
                v[t] = fmaxf(v[t], __shfl_xor(v[t], 16, 64));
                v[t] = fmaxf(v[t], __shfl_xor(v[t], 32, 64));
            }
            float vs = quad == 0 ? v[0] : quad == 1 ? v[1] : quad == 2 ? v[2] : v[3];
            outv = fmaxf(vs + b2v, 0.f);
        }
        float hv = outv + res;
        h[(size_t)node * HID + lane] = hv;
        if (fin) {
            float v = hv * wov;
#pragma unroll
            for (int m = 32; m >= 1; m >>= 1) v += __shfl_xor(v, m, 64);
            if (lane == 0) outp[node] = v + bo[0];
        }
    }
}

extern "C" void kernel_launch(void* const* d_in, const int* in_sizes, int n_in,
                              void* d_out, int out_size, void* d_ws, size_t ws_size,
                              hipStream_t stream) {
    const float* x  = (const float*)d_in[0];
    const int*   ei = (const int*)d_in[1];
    const float* Wp = (const float*)d_in[2];
    const float* bp = (const float*)d_in[3];
    const float* W1 = (const float*)d_in[4];
    const float* b1 = (const float*)d_in[5];
    const float* W2 = (const float*)d_in[6];
    const float* b2 = (const float*)d_in[7];
    const float* Wo = (const float*)d_in[8];
    const float* bo = (const float*)d_in[9];
    float* out = (float*)d_out;

    const int E = in_sizes[1] / 2;
    const int N = NN;
    const int* srcp = ei;
    const int* dstp = ei + E;

    // workspace layout
    float* h  = (float*)d_ws;                       // N*HID f32
    float* Pb = h + (size_t)N * HID;                // N*HID f32
    unsigned short* Qb = (unsigned short*)(Pb + (size_t)N * HID);  // N*HID bf16
    int* deg    = (int*)(Qb + (size_t)N * HID);     // N
    int* off    = deg + N;                          // N
    int* bincnt = off + N;                          // NB
    int* bincur = bincnt + NB;                      // NB (adjacent for one zero)
    int* binoff = bincur + NB;                      // NB
    unsigned* bscratch = (unsigned*)(binoff + NB);  // E
    unsigned short* csr = (unsigned short*)(bscratch + E);  // E ushort

    int nbE = (E + 255) / 256;

    k_zero<<<(2 * NB + 255) / 256, 256, 0, stream>>>(bincnt, 2 * NB);
    k_binhist<<<256, 256, 0, stream>>>(dstp, bincnt, E);
    k_binscan<<<1, 256, 0, stream>>>(bincnt, binoff);
    k_binscatter<<<nbE, 256, 0, stream>>>(srcp, dstp, binoff, bincur, bscratch, E);
    k_binsort<<<NB, 256, 0, stream>>>(bscratch, bincnt, binoff, csr, deg, off);

    k_proj4<<<N / 16, 256, 0, stream>>>(x, Wp, bp, h);
    const int EDGE_BLOCKS = 2048;
    const int NW = EDGE_BLOCKS * 256 / 64;
    const int PQ_BLOCKS = (N / 16 + 3) / 4;  // 782
    for (int l = 0; l < NLAYERS; l++) {
        k_pq_mfma<<<PQ_BLOCKS, 256, 0, stream>>>(h, W1, b1, Pb, Qb, l);
        k_edge<<<EDGE_BLOCKS, 256, 0, stream>>>(Pb, Qb, W2, b2, off, deg, csr, h, l, NW,
                                                l == NLAYERS - 1 ? 1 : 0, Wo, bo, out);
    }
}

// Round 6
// 367.146 us; speedup vs baseline: 1.6493x; 1.6493x over previous
//
#include <hip/hip_runtime.h>

#define NN 50000
#define IN_DIM 128
#define HID 64
#define NLAYERS 3
#define PART_SZ 6250  // NN/8 — one contiguous node range per XCD (blockIdx&7)

typedef __attribute__((ext_vector_type(8))) short bf16x8;
typedef __attribute__((ext_vector_type(4))) float f32x4;

__device__ __forceinline__ unsigned f2bf(float f) {
    unsigned u = __float_as_uint(f);
    return (u + 0x7fffu + ((u >> 16) & 1u)) >> 16;  // round-to-nearest-even
}

// Pack two fp32 -> packed bf16 pair (a -> lo, b -> hi), round-half-up.
__device__ __forceinline__ unsigned pk2bf(float a, float b) {
    return __builtin_amdgcn_perm(__float_as_uint(b) + 0x8000u,
                                 __float_as_uint(a) + 0x8000u, 0x07060302u);
}

// q = packed bf16 pair. Returns packed bf16 pair of relu(q + p).
__device__ __forceinline__ unsigned pack_r(unsigned q, float pA, float pB) {
    float lo = fmaxf(__uint_as_float(q << 16) + pA, 0.f);
    float hi = fmaxf(__uint_as_float(q & 0xffff0000u) + pB, 0.f);
    return pk2bf(lo, hi);
}

__global__ void k_zero(int* __restrict__ p, int n) {
    int i = blockIdx.x * blockDim.x + threadIdx.x;
    if (i < n) p[i] = 0;
}

// Partitioned degree count: block b handles dst range [(b&7)*PART_SZ, +PART_SZ).
// All writes/atomics for a node range come from one block group (-> one XCD
// under round-robin dispatch): no cross-XCD false sharing. Atomic depth ~16.
__global__ void __launch_bounds__(256) k_count_part(const int* __restrict__ dst,
                                                    int* __restrict__ deg, int E) {
    int lo = (blockIdx.x & 7) * PART_SZ, hi = lo + PART_SZ;
    int stride = (gridDim.x >> 3) * 256;
    for (int e = (blockIdx.x >> 3) * 256 + threadIdx.x; e < E; e += stride) {
        int d = dst[e];
        if (d >= lo && d < hi) atomicAdd(&deg[d], 1);
    }
}

// 3-kernel exclusive scan over deg[N] -> off[N]
__global__ void k_scan_partial(const int* __restrict__ deg, int* __restrict__ part, int n) {
    __shared__ int s[256];
    int i = blockIdx.x * 256 + threadIdx.x;
    s[threadIdx.x] = (i < n) ? deg[i] : 0;
    __syncthreads();
    for (int d = 128; d > 0; d >>= 1) {
        if (threadIdx.x < d) s[threadIdx.x] += s[threadIdx.x + d];
        __syncthreads();
    }
    if (threadIdx.x == 0) part[blockIdx.x] = s[0];
}

__global__ void k_scan_root(int* part, int nb) {
    __shared__ int s[256];
    int t = threadIdx.x;
    int v = (t < nb) ? part[t] : 0;
    s[t] = v;
    __syncthreads();
    for (int d = 1; d < 256; d <<= 1) {
        int add = (t >= d) ? s[t - d] : 0;
        __syncthreads();
        s[t] += add;
        __syncthreads();
    }
    if (t < nb) part[t] = s[t] - v;
}

__global__ void k_scan_final(const int* __restrict__ deg, const int* __restrict__ part,
                             int* __restrict__ off, int n) {
    __shared__ int s[256];
    int t = threadIdx.x;
    int i = blockIdx.x * 256 + t;
    int v = (i < n) ? deg[i] : 0;
    s[t] = v;
    __syncthreads();
    for (int d = 1; d < 256; d <<= 1) {
        int add = (t >= d) ? s[t - d] : 0;
        __syncthreads();
        s[t] += add;
        __syncthreads();
    }
    if (i < n) off[i] = part[blockIdx.x] + s[t] - v;
}

// Partitioned scatter into ushort CSR; same block->range mapping as count.
__global__ void __launch_bounds__(256) k_scatter_part(
    const int* __restrict__ src, const int* __restrict__ dst,
    const int* __restrict__ off, int* __restrict__ cursor,
    unsigned short* __restrict__ csr, int E) {
    int lo = (blockIdx.x & 7) * PART_SZ, hi = lo + PART_SZ;
    int stride = (gridDim.x >> 3) * 256;
    for (int e = (blockIdx.x >> 3) * 256 + threadIdx.x; e < E; e += stride) {
        int d = dst[e];
        if (d >= lo && d < hi) {
            int pos = atomicAdd(&cursor[d], 1);
            csr[off[d] + pos] = (unsigned short)src[e];
        }
    }
}

// h = x @ Wp + bp. Wave handles 4 nodes; weight loads amortized 4x.
__global__ void k_proj4(const float* __restrict__ x, const float* __restrict__ Wp,
                        const float* __restrict__ bp, float* __restrict__ h) {
    __shared__ float xs[4][4][IN_DIM];
    int lane = threadIdx.x & 63, wave = threadIdx.x >> 6;
    int node0 = blockIdx.x * 16 + wave * 4;
#pragma unroll
    for (int n = 0; n < 4; n++) {
        xs[wave][n][lane]      = x[(size_t)(node0 + n) * IN_DIM + lane];
        xs[wave][n][64 + lane] = x[(size_t)(node0 + n) * IN_DIM + 64 + lane];
    }
    __syncthreads();
    float bv = bp[lane];
    float acc[4] = {bv, bv, bv, bv};
#pragma unroll
    for (int k = 0; k < IN_DIM; k += 4) {
        float w0 = Wp[(k + 0) * HID + lane];
        float w1 = Wp[(k + 1) * HID + lane];
        float w2 = Wp[(k + 2) * HID + lane];
        float w3 = Wp[(k + 3) * HID + lane];
#pragma unroll
        for (int n = 0; n < 4; n++) {
            float4 xv = *(const float4*)&xs[wave][n][k];
            acc[n] = fmaf(xv.x, w0, acc[n]);
            acc[n] = fmaf(xv.y, w1, acc[n]);
            acc[n] = fmaf(xv.z, w2, acc[n]);
            acc[n] = fmaf(xv.w, w3, acc[n]);
        }
    }
#pragma unroll
    for (int n = 0; n < 4; n++) h[(size_t)(node0 + n) * HID + lane] = acc[n];
}

// [P|Q] = h @ [W1top-W1bot | W1bot] + [b1|0] via MFMA. One wave per 16 nodes.
__global__ void __launch_bounds__(256) k_pq_mfma(
    const float* __restrict__ h, const float* __restrict__ W1,
    const float* __restrict__ b1, float* __restrict__ P,
    unsigned short* __restrict__ Qb, int layer) {
    int lane = threadIdx.x & 63, wave = threadIdx.x >> 6;
    int col = lane & 15, quad = lane >> 4;
    int node0 = (blockIdx.x * 4 + wave) * 16;
    if (node0 >= NN) return;
    const float* W1l = W1 + layer * 2 * HID * HID;

    bf16x8 bfr[8][2];
#pragma unroll
    for (int t = 0; t < 8; t++)
#pragma unroll
        for (int hf = 0; hf < 2; hf++) {
            uint4 u;
#pragma unroll
            for (int jp = 0; jp < 4; jp++) {
                int k0 = hf * 32 + quad * 8 + jp * 2;
                float w0, w1v;
                if (t < 4) {
                    int n = t * 16 + col;
                    w0  = W1l[k0 * HID + n] - W1l[(HID + k0) * HID + n];
                    w1v = W1l[(k0 + 1) * HID + n] - W1l[(HID + k0 + 1) * HID + n];
                } else {
                    int n = (t - 4) * 16 + col;
                    w0  = W1l[(HID + k0) * HID + n];
                    w1v = W1l[(HID + k0 + 1) * HID + n];
                }
                ((unsigned*)&u)[jp] = pk2bf(w0, w1v);
            }
            bfr[t][hf] = __builtin_bit_cast(bf16x8, u);
        }

    const float* hrow = h + (size_t)(node0 + col) * HID;
    float4 ha0 = *(const float4*)(hrow + quad * 8);
    float4 ha1 = *(const float4*)(hrow + quad * 8 + 4);
    float4 hb0 = *(const float4*)(hrow + 32 + quad * 8);
    float4 hb1 = *(const float4*)(hrow + 32 + quad * 8 + 4);
    uint4 au, bu;
    au.x = pk2bf(ha0.x, ha0.y); au.y = pk2bf(ha0.z, ha0.w);
    au.z = pk2bf(ha1.x, ha1.y); au.w = pk2bf(ha1.z, ha1.w);
    bu.x = pk2bf(hb0.x, hb0.y); bu.y = pk2bf(hb0.z, hb0.w);
    bu.z = pk2bf(hb1.x, hb1.y); bu.w = pk2bf(hb1.z, hb1.w);
    bf16x8 a0 = __builtin_bit_cast(bf16x8, au);
    bf16x8 a1 = __builtin_bit_cast(bf16x8, bu);

#pragma unroll
    for (int t = 0; t < 8; t++) {
        f32x4 c = __builtin_amdgcn_mfma_f32_16x16x32_bf16(a0, bfr[t][0], (f32x4)(0.f), 0, 0, 0);
        c = __builtin_amdgcn_mfma_f32_16x16x32_bf16(a1, bfr[t][1], c, 0, 0, 0);
        if (t < 4) {
            float bv = b1[layer * HID + t * 16 + col];
#pragma unroll
            for (int r = 0; r < 4; r++)
                P[(size_t)(node0 + quad * 4 + r) * HID + t * 16 + col] = c[r] + bv;
        } else {
#pragma unroll
            for (int r = 0; r < 4; r++)
                Qb[(size_t)(node0 + quad * 4 + r) * HID + (t - 4) * 16 + col] =
                    (unsigned short)f2bf(c[r]);
        }
    }
}

// One wave per dst node. 16 edges/batch via mfma_f32_16x16x32_bf16.
// Pad lanes replicate edge b0 (valid). When fin!=0, also emit out = h@Wo+bo.
__global__ void __launch_bounds__(256) k_edge(
    const float* __restrict__ P, const unsigned short* __restrict__ Qb,
    const float* __restrict__ W2, const float* __restrict__ b2,
    const int* __restrict__ off, const int* __restrict__ deg,
    const unsigned short* __restrict__ csr, float* __restrict__ h, int layer, int nw,
    int fin, const float* __restrict__ Wo, const float* __restrict__ bo,
    float* __restrict__ outp) {
    int lane = threadIdx.x & 63;
    int col = lane & 15, quad = lane >> 4;
    int wid = (blockIdx.x * blockDim.x + threadIdx.x) >> 6;

    const float* W2l = W2 + layer * HID * HID;
    bf16x8 bfr[4][2];
#pragma unroll
    for (int t = 0; t < 4; t++)
#pragma unroll
        for (int hf = 0; hf < 2; hf++) {
            uint4 u;
#pragma unroll
            for (int jp = 0; jp < 4; jp++) {
                int k0 = hf * 32 + quad * 8 + jp * 2;
                ((unsigned*)&u)[jp] = pk2bf(W2l[k0 * HID + t * 16 + col],
                                            W2l[(k0 + 1) * HID + t * 16 + col]);
            }
            bfr[t][hf] = __builtin_bit_cast(bf16x8, u);
        }
    float b2v = b2[layer * HID + lane];
    float wov = fin ? Wo[lane] : 0.f;

    for (int node = wid; node < NN; node += nw) {
        int start = __builtin_amdgcn_readfirstlane(off[node]);
        int cnt   = __builtin_amdgcn_readfirstlane(deg[node]);
        float res = h[(size_t)node * HID + lane];
        float outv = 0.f;
        if (cnt > 0) {
            const float4* prow = (const float4*)(P + (size_t)node * HID);
            float4 pA = prow[quad * 2], pB = prow[quad * 2 + 1];
            float4 pC = prow[8 + quad * 2], pD = prow[8 + quad * 2 + 1];
            f32x4 mx[4];
#pragma unroll
            for (int t = 0; t < 4; t++) mx[t] = (f32x4)(-3.4e38f);
            for (int b0 = 0; b0 < cnt; b0 += 16) {
                int idx = b0 + col;
                int s = csr[start + (idx < cnt ? idx : b0)];
                const uint4* qrow = (const uint4*)(Qb + (size_t)s * HID);
                uint4 q0 = qrow[quad];
                uint4 q1 = qrow[4 + quad];
                uint4 a0u, a1u;
                a0u.x = pack_r(q0.x, pA.x, pA.y);
                a0u.y = pack_r(q0.y, pA.z, pA.w);
                a0u.z = pack_r(q0.z, pB.x, pB.y);
                a0u.w = pack_r(q0.w, pB.z, pB.w);
                a1u.x = pack_r(q1.x, pC.x, pC.y);
                a1u.y = pack_r(q1.y, pC.z, pC.w);
                a1u.z = pack_r(q1.z, pD.x, pD.y);
                a1u.w = pack_r(q1.w, pD.z, pD.w);
                bf16x8 a0 = __builtin_bit_cast(bf16x8, a0u);
                bf16x8 a1 = __builtin_bit_cast(bf16x8, a1u);
#pragma unroll
                for (int t = 0; t < 4; t++) {
                    f32x4 c = __builtin_amdgcn_mfma_f32_16x16x32_bf16(
                        a0, bfr[t][0], (f32x4)(0.f), 0, 0, 0);
                    c = __builtin_amdgcn_mfma_f32_16x16x32_bf16(
                        a1, bfr[t][1], c, 0, 0, 0);
#pragma unroll
                    for (int r = 0; r < 4; r++)
                        mx[t][r] = fmaxf(mx[t][r], c[r]);
                }
            }
            float v[4];
#pragma unroll
            for (int t = 0; t < 4; t++) {
                v[t] = fmaxf(fmaxf(mx[t][0], mx[t][1]), fmaxf(mx[t][2], mx[t][3]));
                v[t] = fmaxf(v[t], __shfl_xor(v[t], 16, 64));
                v[t] = fmaxf(v[t], __shfl_xor(v[t], 32, 64));
            }
            float vs = quad == 0 ? v[0] : quad == 1 ? v[1] : quad == 2 ? v[2] : v[3];
            outv = fmaxf(vs + b2v, 0.f);
        }
        float hv = outv + res;
        h[(size_t)node * HID + lane] = hv;
        if (fin) {
            float v = hv * wov;
#pragma unroll
            for (int m = 32; m >= 1; m >>= 1) v += __shfl_xor(v, m, 64);
            if (lane == 0) outp[node] = v + bo[0];
        }
    }
}

extern "C" void kernel_launch(void* const* d_in, const int* in_sizes, int n_in,
                              void* d_out, int out_size, void* d_ws, size_t ws_size,
                              hipStream_t stream) {
    const float* x  = (const float*)d_in[0];
    const int*   ei = (const int*)d_in[1];
    const float* Wp = (const float*)d_in[2];
    const float* bp = (const float*)d_in[3];
    const float* W1 = (const float*)d_in[4];
    const float* b1 = (const float*)d_in[5];
    const float* W2 = (const float*)d_in[6];
    const float* b2 = (const float*)d_in[7];
    const float* Wo = (const float*)d_in[8];
    const float* bo = (const float*)d_in[9];
    float* out = (float*)d_out;

    const int E = in_sizes[1] / 2;
    const int N = NN;
    const int* srcp = ei;
    const int* dstp = ei + E;

    // workspace layout
    float* h  = (float*)d_ws;                       // N*HID f32
    float* Pb = h + (size_t)N * HID;                // N*HID f32
    unsigned short* Qb = (unsigned short*)(Pb + (size_t)N * HID);  // N*HID bf16
    int* deg    = (int*)(Qb + (size_t)N * HID);     // N
    int* cursor = deg + N;                          // N (adjacent for one zero)
    int* off    = cursor + N;                       // N
    int* part   = off + N;                          // 256
    unsigned short* csr = (unsigned short*)(part + 256);  // E ushort

    int nbN = (N + 255) / 256;  // 196

    k_zero<<<(2 * N + 255) / 256, 256, 0, stream>>>(deg, 2 * N);
    k_count_part<<<512, 256, 0, stream>>>(dstp, deg, E);
    k_scan_partial<<<nbN, 256, 0, stream>>>(deg, part, N);
    k_scan_root<<<1, 256, 0, stream>>>(part, nbN);
    k_scan_final<<<nbN, 256, 0, stream>>>(deg, part, off, N);
    k_scatter_part<<<512, 256, 0, stream>>>(srcp, dstp, off, cursor, csr, E);

    k_proj4<<<N / 16, 256, 0, stream>>>(x, Wp, bp, h);
    const int EDGE_BLOCKS = 2048;
    const int NW = EDGE_BLOCKS * 256 / 64;
    const int PQ_BLOCKS = (N / 16 + 3) / 4;  // 782
    for (int l = 0; l < NLAYERS; l++) {
        k_pq_mfma<<<PQ_BLOCKS, 256, 0, stream>>>(h, W1, b1, Pb, Qb, l);
        k_edge<<<EDGE_BLOCKS, 256, 0, stream>>>(Pb, Qb, W2, b2, off, deg, csr, h, l, NW,
                                                l == NLAYERS - 1 ? 1 : 0, Wo, bo, out);
    }
}